// Round 12
// baseline (4490.605 us; speedup 1.0000x reference)
//
#include <hip/hip_runtime.h>

// ---------------------------------------------------------------------------
// TTS forward on MI355X.
//   embed -> conv1(+BN+ReLU) -> conv2(+BN+ReLU) -> FUSED persistent kernel:
//     [64 enc blocks | 68 dec blocks | 60 prep blocks], one launch.
// Round 15: overlap all decoder weight prep (packrec/bsum/weff/bdec/cast/
// projg/mask) with the latency-bound encoder inside one fused kernel.
// Prep writes via sc0/sc1 write-through; counters (packdone/encdone/
// prepdone) gate enc weight loads and dec start. Enc epilogue (dec slot 0 +
// cel) via atomics. Enc = R14 body (4 domains x 16 blocks); dec = R13/R14
// body (2 groups x 32 core + mel + gate). Exchange machinery unchanged.
// ---------------------------------------------------------------------------

typedef float f4 __attribute__((ext_vector_type(4)));
typedef _Float16 h8 __attribute__((ext_vector_type(8)));
typedef _Float16 half_t;
typedef unsigned long long u64;

#define B_    32
#define LTXT  256
#define TMEL  800
#define EE    512
#define HH    512
#define DD    1024
#define MM    128
#define NROWS 8192          // B_*LTXT
#define GATE_OFF 3276800    // B_*TMEL*MM
#define MASK_OFF 3302400    // + B_*TMEL

#define RING_D 801          // decoder ring slots per group (32KB, never reused)
#define RING_E 257          // encoder ring slots per domain (16KB, never reused)
#define HOP    13           // coprime with both
#define ENCTOT 1048576      // 2048*512
#define PREPN  60
#define ENCN   64

// workspace offsets (bytes)
#define WS_MBE        0ull             // enc mailboxes: 4 dom x 16 cons x 64 u32 = 16 KiB
#define WS_MBD        16384ull         // dec mailboxes: 2 groups x 34 x 64 u32
#define WS_CNT        40960ull         // counters: [0]=packdone [16]=encdone [32]=prepdone
#define WS_HENC       49152ull         // [RING_E][4 dom][16KB]
#define WS_ZERO_BYTES 114688ull        // mailboxes + counters + henc slot 0 (64KB)
#define WS_HD         16891904ull      // 2 groups * RING_D * 32768
#define WS_BUFX       69386240ull      // 8 MiB
#define WS_BUFY       77774848ull      // 8 MiB
#define WS_CONVF      86163456ull      // 16 MiB (reused by WEFF/W0 after convs)
#define WS_WEFF       86163456ull
#define WS_W0         94552064ull
#define WS_WP1        102940672ull
#define WS_WP2        104513536ull
#define WS_WIHP       106086400ull     // 4 MiB
#define WS_WHHP       110280704ull     // 4 MiB
#define WS_BSUM       114475008ull
#define WS_BEFF       114491392ull
#define WS_B0         114507776ull
#define WS_MEAN       114524160ull
#define WS_RSTD       114526208ull
#define WS_PROJW      114528256ull
#define WS_PROJG      114790400ull
#define WS_CEL        114823168ull
// total ~114.95 MB

__device__ __forceinline__ float sigm(float x) { return 1.f / (1.f + __expf(-x)); }
__device__ __forceinline__ float tanh_f(float x) {
    float e = __expf(2.f * x);
    return 1.f - 2.f / (e + 1.f);
}

// return-less atomic swap: executes at coherence point, line stays L3-resident
__device__ __forceinline__ void st_atom64(void* p, u64 v) {
    asm volatile("global_atomic_swap_x2 %0, %1, off" :: "v"(p), "v"(v) : "memory");
}
__device__ __forceinline__ void st_atom32(void* p, unsigned v) {
    asm volatile("global_atomic_swap %0, %1, off" :: "v"(p), "v"(v) : "memory");
}
// write-through 4B store (commit to L3 coherence point)
__device__ __forceinline__ void st_wt32(void* p, unsigned v) {
    asm volatile("global_store_dword %0, %1, off sc0 sc1" :: "v"(p), "v"(v) : "memory");
}
__device__ __forceinline__ unsigned f2u(float f) {
    union { float f; unsigned u; } c; c.f = f; return c.u;
}

// ---------------- front-end kernels ----------------

__global__ void k_embed(const int* __restrict__ x, const float* __restrict__ emb,
                        half_t* __restrict__ out) {
    int row = blockIdx.x;
    int tok = x[row];
    const float* e = emb + (size_t)tok * EE;
    half_t* o = out + (size_t)row * EE;
    for (int c = threadIdx.x; c < EE; c += blockDim.x) o[c] = (half_t)e[c];
}

__global__ void k_packconvw(const float* __restrict__ w, half_t* __restrict__ wp) {
    int idx = blockIdx.x * 256 + threadIdx.x;
    if (idx >= 3 * EE * EE) return;
    int s = idx / (EE * EE);
    int rem = idx - s * EE * EE;
    int eo = rem >> 9, ei = rem & 511;
    wp[idx] = (half_t)w[(size_t)eo * (EE * 3) + ei * 3 + s];
}

__global__ __launch_bounds__(256) void k_conv(const half_t* __restrict__ A,
                                              const half_t* __restrict__ Wp,
                                              const float* __restrict__ bias,
                                              float* __restrict__ out) {
    const int nt = blockIdx.x, et = blockIdx.y;
    const int tid = threadIdx.x;
    const int wv = tid >> 6, l = tid & 63, quad = l >> 4, lo = l & 15;
    const int rowA = nt * 64 + wv * 16 + lo;
    const int eo = et * 16 + lo;
    f4 acc = {0.f, 0.f, 0.f, 0.f};
    for (int s = 0; s < 3; ++s) {
        int lsp = (rowA & 255) + s - 1;
        bool valid = (lsp >= 0) && (lsp < 256);
        int rs = rowA + s - 1;
        rs = rs < 0 ? 0 : (rs > NROWS - 1 ? NROWS - 1 : rs);
        const half_t* ab = A + (size_t)rs * EE;
        const half_t* wb = Wp + ((size_t)s * EE + eo) * EE;
#pragma unroll 4
        for (int ks = 0; ks < 16; ++ks) {
            h8 a = {0, 0, 0, 0, 0, 0, 0, 0};
            if (valid) a = *(const h8*)(ab + ks * 32 + quad * 8);
            h8 b = *(const h8*)(wb + ks * 32 + quad * 8);
            acc = __builtin_amdgcn_mfma_f32_16x16x32_f16(a, b, acc, 0, 0, 0);
        }
    }
    const int orow = nt * 64 + wv * 16 + quad * 4;
    const float bv = bias[eo];
#pragma unroll
    for (int r = 0; r < 4; ++r) out[(size_t)(orow + r) * EE + eo] = acc[r] + bv;
}

__global__ __launch_bounds__(256) void k_bnstats(const float* __restrict__ x,
                                                 float* __restrict__ mean,
                                                 float* __restrict__ rstd) {
    const int c = blockIdx.x;
    float s = 0.f, ss = 0.f;
    for (int n = threadIdx.x; n < NROWS; n += 256) {
        float v = x[(size_t)n * EE + c];
        s += v; ss += v * v;
    }
#pragma unroll
    for (int off = 32; off > 0; off >>= 1) { s += __shfl_down(s, off); ss += __shfl_down(ss, off); }
    __shared__ float as[4], ass[4];
    int wv = threadIdx.x >> 6;
    if ((threadIdx.x & 63) == 0) { as[wv] = s; ass[wv] = ss; }
    __syncthreads();
    if (threadIdx.x == 0) {
        float S = as[0] + as[1] + as[2] + as[3];
        float SS = ass[0] + ass[1] + ass[2] + ass[3];
        float m = S / (float)NROWS;
        float var = SS / (float)NROWS - m * m;
        mean[c] = m;
        rstd[c] = rsqrtf(var + 1e-5f);
    }
}

__global__ void k_bnapply(const float* __restrict__ x, const float* __restrict__ mean,
                          const float* __restrict__ rstd, const float* __restrict__ g,
                          const float* __restrict__ beta, half_t* __restrict__ out) {
    int idx = blockIdx.x * 256 + threadIdx.x;
    if (idx >= NROWS * EE) return;
    int c = idx & (EE - 1);
    float v = (x[idx] - mean[c]) * rstd[c] * g[c] + beta[c];
    out[idx] = (half_t)(v > 0.f ? v : 0.f);
}

// ---------------- fused persistent kernel ----------------
// Grid 192 x 512: j<64 enc | 64<=j<132 dec | j>=132 prep.
__global__ __launch_bounds__(512) void k_fused(
        const float* __restrict__ wihf, const float* __restrict__ whhf,
        const float* __restrict__ bihf, const float* __restrict__ bhhf,
        const float* __restrict__ wihb, const float* __restrict__ whhb,
        const float* __restrict__ bihb, const float* __restrict__ bhhb,
        const float* __restrict__ dwih, const float* __restrict__ dwhh,
        const float* __restrict__ dbih, const float* __restrict__ dbhh,
        const float* __restrict__ projw, const float* __restrict__ projb,
        const float* __restrict__ gatew, const float* __restrict__ gateb,
        const int* __restrict__ tlens, const int* __restrict__ mlens,
        char* __restrict__ ws, float* __restrict__ out) {
    const int j = blockIdx.x;
    const int tid = threadIdx.x;
    const int wv = tid >> 6, l = tid & 63, quad = l >> 4, lo = l & 15;

    unsigned* mbE = (unsigned*)(ws + WS_MBE);
    unsigned* mbD = (unsigned*)(ws + WS_MBD);
    unsigned* cnt = (unsigned*)(ws + WS_CNT);
    half_t* henc = (half_t*)(ws + WS_HENC);
    half_t* hd = (half_t*)(ws + WS_HD);
    half_t* X = (half_t*)(ws + WS_BUFX);
    half_t* wihp = (half_t*)(ws + WS_WIHP);
    half_t* whhp = (half_t*)(ws + WS_WHHP);
    float* bsum = (float*)(ws + WS_BSUM);
    half_t* weff = (half_t*)(ws + WS_WEFF);
    half_t* w0 = (half_t*)(ws + WS_W0);
    float* beff = (float*)(ws + WS_BEFF);
    float* b0 = (float*)(ws + WS_B0);
    half_t* projwb = (half_t*)(ws + WS_PROJW);
    half_t* projg = (half_t*)(ws + WS_PROJG);
    float* cel = (float*)(ws + WS_CEL);

    __shared__ __align__(16) char smem[44544];

    if (j >= 132) {
        // ================= prep blocks =================
        const int nthr = PREPN * 512;
        const int gtid = (j - 132) * 512 + tid;
        // phase 1: pack recurrent weights (pairs -> dword wt stores) + bsum
        for (int a = 0; a < 4; ++a) {
            const float* src = (a == 0) ? wihf : (a == 1) ? wihb : (a == 2) ? whhf : whhb;
            half_t* dst = (a < 2) ? (wihp + (size_t)a * ENCTOT) : (whhp + (size_t)(a - 2) * ENCTOT);
            for (int pr2 = gtid; pr2 < ENCTOT / 2; pr2 += nthr) {
                int p = pr2 >> 8, k0 = (pr2 & 255) * 2;
                int he = p >> 2, g = p & 3;
                const float* s2 = src + ((size_t)(g * HH + he)) * 512 + k0;
                union { half_t h[2]; unsigned u; } pk;
                pk.h[0] = (half_t)s2[0]; pk.h[1] = (half_t)s2[1];
                st_wt32(dst + (size_t)p * 512 + k0, pk.u);
            }
        }
        for (int p = gtid; p < 4096; p += nthr) {
            int dir = p >> 11, pp = p & 2047, he = pp >> 2, g = pp & 3;
            int row = g * HH + he;
            float v = dir ? (bihb[row] + bhhb[row]) : (bihf[row] + bhhf[row]);
            st_wt32(bsum + p, f2u(v));
        }
        asm volatile("s_waitcnt vmcnt(0)" ::: "memory");
        if (tid == 0)
            __hip_atomic_fetch_add(cnt + 0, 1u, __ATOMIC_RELAXED, __HIP_MEMORY_SCOPE_AGENT);
        // phase 2: Weff/W0 fold + biases + projection weight casts + mask
        for (int pr2 = gtid; pr2 < (4096 * 1024) / 2; pr2 += nthr) {
            int row = pr2 >> 9, k0 = (pr2 & 511) * 2;
            float v0 = dwhh[(size_t)row * DD + k0], v1 = dwhh[(size_t)row * DD + k0 + 1];
            float a0 = v0, a1 = v1;
            const float* dwr = dwih + (size_t)row * MM;
            for (int m = 0; m < MM; ++m) {
                float dw = dwr[m];
                a0 += dw * projw[(size_t)m * DD + k0];
                a1 += dw * projw[(size_t)m * DD + k0 + 1];
            }
            int p = ((row & (DD - 1)) << 2) | (row >> 10);
            union { half_t h[2]; unsigned u; } pk;
            pk.h[0] = (half_t)a0; pk.h[1] = (half_t)a1;
            st_wt32(weff + (size_t)p * DD + k0, pk.u);
            pk.h[0] = (half_t)v0; pk.h[1] = (half_t)v1;
            st_wt32(w0 + (size_t)p * DD + k0, pk.u);
        }
        for (int p = gtid; p < 4096; p += nthr) {
            int he = p >> 2, g = p & 3;
            int row = g * DD + he;
            float bb = dbih[row] + dbhh[row];
            float acc = bb;
            const float* dwr = dwih + (size_t)row * MM;
            for (int m = 0; m < MM; ++m) acc += dwr[m] * projb[m];
            st_wt32(b0 + p, f2u(bb));
            st_wt32(beff + p, f2u(acc));
        }
        for (int i2 = gtid; i2 < (MM * DD) / 2; i2 += nthr) {
            int i0 = 2 * i2;
            union { half_t h[2]; unsigned u; } pk;
            pk.h[0] = (half_t)projw[i0]; pk.h[1] = (half_t)projw[i0 + 1];
            st_wt32(projwb + i0, pk.u);
        }
        for (int i2 = gtid; i2 < (16 * DD) / 2; i2 += nthr) {
            int i0 = 2 * i2;
            int row = i0 >> 10, k = i0 & (DD - 1);
            union { half_t h[2]; unsigned u; } pk;
            pk.h[0] = (half_t)(row == 0 ? gatew[k] : 0.f);
            pk.h[1] = (half_t)(row == 0 ? gatew[k + 1] : 0.f);
            st_wt32(projg + i0, pk.u);
        }
        for (int i = gtid; i < B_ * TMEL; i += nthr) {
            int b = i / TMEL, t = i - b * TMEL;
            __builtin_nontemporal_store((t > mlens[b]) ? 1.f : 0.f, &out[MASK_OFF + i]);
        }
        asm volatile("s_waitcnt vmcnt(0)" ::: "memory");
        if (tid == 0)
            __hip_atomic_fetch_add(cnt + 32, 1u, __ATOMIC_RELAXED, __HIP_MEMORY_SCOPE_AGENT);
        return;
    }

    if (j < 64) {
        // ================= encoder block (R14 body) =================
        if (tid == 0) {
            while (__hip_atomic_load(cnt + 0, __ATOMIC_RELAXED, __HIP_MEMORY_SCOPE_AGENT) < (unsigned)PREPN)
                __builtin_amdgcn_s_sleep(2);
        }
        __syncthreads();

        const int d = j >> 4, jj = j & 15;
        const int dir = d >> 1, bg = d & 1;
        const int ue = tid >> 4;   // h-elem within block [0,32)
        const int ub = tid & 15;   // batch within group [0,16)

        half_t* s_hd = (half_t*)smem;                       // [16][520]
        float (*s_g)[129] = (float(*)[129])(smem + 16640);  // [16][129]
        float (*s_c)[16] = (float(*)[16])(smem + 24896);    // [32][16]
        float (*s_h)[16] = (float(*)[16])(smem + 26944);    // [32][16]
        half_t (*s_hh)[16] = (half_t(*)[16])(smem + 28992); // [32][16]
        int* s_len = (int*)(smem + 30016);                  // [16]

        if (tid < 16) s_len[tid] = tlens[bg * 16 + tid];
        s_c[ue][ub] = 0.f;
        s_h[ue][ub] = 0.f;

        const int pr = dir * 2048 + jj * 128 + wv * 16 + lo;
        const half_t* wih_b = wihp + (size_t)pr * 512;
        const half_t* whh_b = whhp + (size_t)pr * 512;
        const float bias_n = bsum[pr];

        h8 wihreg[16], whhreg[16];
#pragma unroll
        for (int ks = 0; ks < 16; ++ks) {
            wihreg[ks] = *(const h8*)(wih_b + ks * 32 + quad * 8);
            whhreg[ks] = *(const h8*)(whh_b + ks * 32 + quad * 8);
        }

        int sp = 0, sn = HOP;
        __syncthreads();

        for (int t = 0; t < 256; ++t) {
            if (t > 0) {
                if (wv == 1 && l < 16) {
                    const unsigned want = (unsigned)t;
                    const unsigned* fp = mbE + (size_t)(d * 16 + jj) * 64 + l;
                    while (__hip_atomic_load(fp, __ATOMIC_RELAXED, __HIP_MEMORY_SCOPE_AGENT) < want)
                        __builtin_amdgcn_s_sleep(1);
                }
                __syncthreads();
            }

            const half_t* src = henc + ((size_t)sp * 4 + d) * 8192;
            h8 tmp0 = *(const h8*)(src + (size_t)(tid + 0 * 512) * 8);
            h8 tmp1 = *(const h8*)(src + (size_t)(tid + 1 * 512) * 8);

            const int lb = s_len[lo];
            int tt = (dir == 0) ? t : (lb - 1 - t);
            tt = tt < 0 ? 0 : tt;
            const half_t* xr = X + ((size_t)(bg * 16 + lo) * 256 + tt) * 512;
            f4 accA = {0.f, 0.f, 0.f, 0.f}, accB = {0.f, 0.f, 0.f, 0.f};
#pragma unroll
            for (int ks = 0; ks < 16; ++ks) {
                h8 a = *(const h8*)(xr + ks * 32 + quad * 8);
                accA = __builtin_amdgcn_mfma_f32_16x16x32_f16(a, wihreg[ks], accA, 0, 0, 0);
            }

            {
                int c0 = tid;
                *(h8*)(s_hd + (size_t)(c0 >> 6) * 520 + (c0 & 63) * 8) = tmp0;
                int c1 = tid + 512;
                *(h8*)(s_hd + (size_t)(c1 >> 6) * 520 + (c1 & 63) * 8) = tmp1;
            }
            __syncthreads();

            const half_t* ar = s_hd + (size_t)lo * 520 + quad * 8;
#pragma unroll
            for (int ks = 0; ks < 16; ++ks) {
                h8 a = *(const h8*)(ar + ks * 32);
                accB = __builtin_amdgcn_mfma_f32_16x16x32_f16(a, whhreg[ks], accB, 0, 0, 0);
            }
#pragma unroll
            for (int r = 0; r < 4; ++r) s_g[quad * 4 + r][wv * 16 + lo] = accA[r] + accB[r] + bias_n;
            __syncthreads();
            {
                float gi = s_g[ub][ue * 4 + 0], gf = s_g[ub][ue * 4 + 1];
                float gg = s_g[ub][ue * 4 + 2], go = s_g[ub][ue * 4 + 3];
                float cn = sigm(gf) * s_c[ue][ub] + sigm(gi) * tanh_f(gg);
                float hn = sigm(go) * tanh_f(cn);
                if (t < s_len[ub]) { s_c[ue][ub] = cn; s_h[ue][ub] = hn; }
                s_hh[ue][ub] = (half_t)s_h[ue][ub];
            }
            __syncthreads();
            if (tid < 64 && t < 255) {
                int b2 = tid >> 2, e8 = (tid & 3) * 8;
                union { half_t h[8]; u64 u[2]; } pk;
#pragma unroll
                for (int i = 0; i < 8; ++i) pk.h[i] = s_hh[e8 + i][b2];
                half_t* dst = henc + ((size_t)sn * 4 + d) * 8192 + (size_t)b2 * 512 + jj * 32 + e8;
                st_atom64(dst, pk.u[0]);
                st_atom64(dst + 4, pk.u[1]);
                asm volatile("s_waitcnt vmcnt(0)");
                if (tid < 16)
                    st_atom32(mbE + ((size_t)(d * 16 + tid) * 64 + jj), (unsigned)(t + 1));
            }
            if (t < 255) { sp = sn; sn += HOP; if (sn >= RING_E) sn -= RING_E; }
        }
        // epilogue: dec ring slot 0 + cel via atomics (visible in-kernel), then encdone
        if (!(ue & 1)) {
            union { half_t h[2]; unsigned u; } pk;
            pk.h[0] = (half_t)s_h[ue][ub]; pk.h[1] = (half_t)s_h[ue + 1][ub];
            st_atom32(hd + (size_t)bg * ((size_t)RING_D * 16384) + (size_t)ub * 1024
                      + dir * 512 + jj * 32 + ue, pk.u);
        }
        st_atom32(cel + (size_t)(bg * 16 + ub) * 1024 + dir * 512 + jj * 32 + ue,
                  f2u(s_c[ue][ub]));
        asm volatile("s_waitcnt vmcnt(0)" ::: "memory");
        __syncthreads();
        if (tid == 0)
            __hip_atomic_fetch_add(cnt + 16, 1u, __ATOMIC_RELAXED, __HIP_MEMORY_SCOPE_AGENT);
        return;
    }

    // ================= decoder blocks (R13/R14 body) =================
    if (tid == 0) {
        while (__hip_atomic_load(cnt + 16, __ATOMIC_RELAXED, __HIP_MEMORY_SCOPE_AGENT) < (unsigned)ENCN ||
               __hip_atomic_load(cnt + 32, __ATOMIC_RELAXED, __HIP_MEMORY_SCOPE_AGENT) < (unsigned)PREPN)
            __builtin_amdgcn_s_sleep(2);
    }
    __syncthreads();

    const int dj = j - 64;

    half_t* s_hd = (half_t*)smem;                       // [16][1032]
    float (*s_g)[129] = (float(*)[129])(smem + 33024);  // [16][129]
    float (*s_c)[16] = (float(*)[16])(smem + 41280);    // [32][16]
    half_t (*s_hh)[16] = (half_t(*)[16])(smem + 43328); // [32][16]
    int* s_len = (int*)(smem + 44352);                  // [32]

    if (dj < 64) {
        // ---------------- core recurrence block ----------------
        const int g = dj >> 5, jj = dj & 31;
        half_t* hdG = hd + (size_t)g * ((size_t)RING_D * 16384);
        unsigned* mbG = mbD + (size_t)g * 34 * 64;
        const int ue = tid >> 4;   // h-elem in block [0,32)
        const int ub = tid & 15;   // batch in group [0,16)

        s_c[ue][ub] = cel[(size_t)(g * 16 + ub) * 1024 + jj * 32 + ue];
        const int pr = jj * 128 + wv * 16 + lo;
        const float biasE = beff[pr], bias0 = b0[pr];
        const half_t* wbE = weff + (size_t)pr * 1024;
        const half_t* wb0 = w0 + (size_t)pr * 1024;

        h8 wreg[32];
#pragma unroll
        for (int ks = 0; ks < 32; ++ks)
            wreg[ks] = *(const h8*)(wbE + ks * 32 + quad * 8);

        int sp = 0, sn = HOP;
        __syncthreads();

        for (int t = 1; t <= TMEL; ++t) {
            if (t > 1) {
                if (tid >= 64 && tid < 96) {
                    const unsigned want = (unsigned)(t - 1);
                    const unsigned* fp = mbG + (size_t)jj * 64 + (tid - 64);
                    while (__hip_atomic_load(fp, __ATOMIC_RELAXED, __HIP_MEMORY_SCOPE_AGENT) < want)
                        __builtin_amdgcn_s_sleep(1);
                }
                __syncthreads();
            }

            {
                const half_t* src = hdG + (size_t)sp * 16384;
                h8 tp[4];
#pragma unroll
                for (int i = 0; i < 4; ++i)
                    tp[i] = *(const h8*)(src + (size_t)(tid + i * 512) * 8);
#pragma unroll
                for (int i = 0; i < 4; ++i) {
                    int c = tid + i * 512;
                    *(h8*)(s_hd + (size_t)(c >> 7) * 1032 + (c & 127) * 8) = tp[i];
                }
            }
            __syncthreads();

            const half_t* ar = s_hd + (size_t)lo * 1032 + quad * 8;
            f4 acc = {0.f, 0.f, 0.f, 0.f}, acc2 = {0.f, 0.f, 0.f, 0.f};
            if (t == 1) {
#pragma unroll 8
                for (int ks = 0; ks < 32; ks += 2) {
                    h8 a0 = *(const h8*)(ar + ks * 32);
                    h8 a1 = *(const h8*)(ar + ks * 32 + 32);
                    acc = __builtin_amdgcn_mfma_f32_16x16x32_f16(a0, *(const h8*)(wb0 + ks * 32 + quad * 8), acc, 0, 0, 0);
                    acc2 = __builtin_amdgcn_mfma_f32_16x16x32_f16(a1, *(const h8*)(wb0 + ks * 32 + 32 + quad * 8), acc2, 0, 0, 0);
                }
            } else {
#pragma unroll
                for (int ks = 0; ks < 32; ks += 2) {
                    h8 a0 = *(const h8*)(ar + ks * 32);
                    h8 a1 = *(const h8*)(ar + ks * 32 + 32);
                    acc = __builtin_amdgcn_mfma_f32_16x16x32_f16(a0, wreg[ks], acc, 0, 0, 0);
                    acc2 = __builtin_amdgcn_mfma_f32_16x16x32_f16(a1, wreg[ks + 1], acc2, 0, 0, 0);
                }
            }
            const float bn = (t == 1) ? bias0 : biasE;
#pragma unroll
            for (int r = 0; r < 4; ++r) s_g[quad * 4 + r][wv * 16 + lo] = acc[r] + acc2[r] + bn;
            __syncthreads();
            {
                float gi = s_g[ub][ue * 4 + 0], gf = s_g[ub][ue * 4 + 1];
                float gg = s_g[ub][ue * 4 + 2], go = s_g[ub][ue * 4 + 3];
                float cn = sigm(gf) * s_c[ue][ub] + sigm(gi) * tanh_f(gg);
                s_c[ue][ub] = cn;
                s_hh[ue][ub] = (half_t)(sigm(go) * tanh_f(cn));
            }
            __syncthreads();
            if (tid < 64) {
                int b2 = tid >> 2, e8 = (tid & 3) * 8;
                union { half_t h[8]; u64 u[2]; } pk;
#pragma unroll
                for (int i = 0; i < 8; ++i) pk.h[i] = s_hh[e8 + i][b2];
                half_t* dst = hdG + (size_t)sn * 16384 + (size_t)b2 * 1024 + jj * 32 + e8;
                st_atom64(dst, pk.u[0]);
                st_atom64(dst + 4, pk.u[1]);
                asm volatile("s_waitcnt vmcnt(0)");
                if (tid < 34)
                    st_atom32(mbG + ((size_t)tid * 64 + jj), (unsigned)t);
            }
            sp = sn; sn += HOP; if (sn >= RING_D) sn -= RING_D;
        }
    } else {
        // ---------------- projection consumer blocks ----------------
        const int p = dj - 64;
        const int g = p >> 1;                  // group
        const bool meld = ((p & 1) == 0);      // 0 = mel, 1 = gate
        half_t* hdG = hd + (size_t)g * ((size_t)RING_D * 16384);
        unsigned* mbG = mbD + (size_t)g * 34 * 64;
        const int cons = meld ? 32 : 33;
        const bool duty = meld || (wv == 0);
        const half_t* pw = meld ? (projwb + (size_t)(wv * 16 + lo) * 1024)
                                : (projg + (size_t)lo * 1024);
        const float biasP = meld ? projb[wv * 16 + lo] : gateb[0];

        h8 pwreg[32];
        if (duty) {
#pragma unroll
            for (int ks = 0; ks < 32; ++ks)
                pwreg[ks] = *(const h8*)(pw + ks * 32 + quad * 8);
        }
        if (tid < 32) s_len[tid] = mlens[tid];

        int spP = HOP;
        __syncthreads();

        for (int t = 1; t <= TMEL; ++t) {
            if (tid < 32) {
                const unsigned want = (unsigned)t;
                const unsigned* fp = mbG + (size_t)cons * 64 + tid;
                while (__hip_atomic_load(fp, __ATOMIC_RELAXED, __HIP_MEMORY_SCOPE_AGENT) < want)
                    __builtin_amdgcn_s_sleep(1);
            }
            __syncthreads();

            {
                const half_t* src = hdG + (size_t)spP * 16384;
                h8 tp[4];
#pragma unroll
                for (int i = 0; i < 4; ++i)
                    tp[i] = *(const h8*)(src + (size_t)(tid + i * 512) * 8);
#pragma unroll
                for (int i = 0; i < 4; ++i) {
                    int c = tid + i * 512;
                    *(h8*)(s_hd + (size_t)(c >> 7) * 1032 + (c & 127) * 8) = tp[i];
                }
            }
            __syncthreads();

            if (duty) {
                const half_t* ar = s_hd + (size_t)lo * 1032 + quad * 8;
                f4 accm = {0.f, 0.f, 0.f, 0.f}, accm2 = {0.f, 0.f, 0.f, 0.f};
#pragma unroll
                for (int ks = 0; ks < 32; ks += 2) {
                    h8 a0 = *(const h8*)(ar + ks * 32);
                    h8 a1 = *(const h8*)(ar + ks * 32 + 32);
                    accm = __builtin_amdgcn_mfma_f32_16x16x32_f16(a0, pwreg[ks], accm, 0, 0, 0);
                    accm2 = __builtin_amdgcn_mfma_f32_16x16x32_f16(a1, pwreg[ks + 1], accm2, 0, 0, 0);
                }
                accm[0] += accm2[0]; accm[1] += accm2[1];
                accm[2] += accm2[2]; accm[3] += accm2[3];
                const int pos = t - 1;
                if (meld) {
#pragma unroll
                    for (int r = 0; r < 4; ++r) {
                        int b = g * 16 + quad * 4 + r;
                        float v = accm[r] + biasP;
                        if (pos > s_len[b]) v = 0.f;
                        __builtin_nontemporal_store(v,
                            &out[(size_t)b * (TMEL * MM) + (size_t)pos * MM + wv * 16 + lo]);
                    }
                } else if (lo == 0) {
#pragma unroll
                    for (int r = 0; r < 4; ++r) {
                        int b = g * 16 + quad * 4 + r;
                        float v = accm[r] + biasP;
                        if (pos > s_len[b]) v = 1000.f;
                        __builtin_nontemporal_store(v, &out[GATE_OFF + (size_t)b * TMEL + pos]);
                    }
                }
            }
            __syncthreads();
            spP += HOP; if (spP >= RING_D) spP -= RING_D;
        }
    }
}

// ---------------------------------------------------------------------------

extern "C" void kernel_launch(void* const* d_in, const int* in_sizes, int n_in,
                              void* d_out, int out_size, void* d_ws, size_t ws_size,
                              hipStream_t stream) {
    const int* x = (const int*)d_in[0];
    const int* tlens = (const int*)d_in[1];
    const int* mlens = (const int*)d_in[3];
    const float* emb = (const float*)d_in[4];
    const float* c1w = (const float*)d_in[5];
    const float* c1b = (const float*)d_in[6];
    const float* bn1g = (const float*)d_in[7];
    const float* bn1b = (const float*)d_in[8];
    const float* c2w = (const float*)d_in[9];
    const float* c2b = (const float*)d_in[10];
    const float* bn2g = (const float*)d_in[11];
    const float* bn2b = (const float*)d_in[12];
    const float* wihf = (const float*)d_in[13];
    const float* whhf = (const float*)d_in[14];
    const float* bihf = (const float*)d_in[15];
    const float* bhhf = (const float*)d_in[16];
    const float* wihb = (const float*)d_in[17];
    const float* whhb = (const float*)d_in[18];
    const float* bihb = (const float*)d_in[19];
    const float* bhhb = (const float*)d_in[20];
    const float* dwih = (const float*)d_in[21];
    const float* dwhh = (const float*)d_in[22];
    const float* dbih = (const float*)d_in[23];
    const float* dbhh = (const float*)d_in[24];
    const float* projw = (const float*)d_in[25];
    const float* projb = (const float*)d_in[26];
    const float* gatew = (const float*)d_in[27];
    const float* gateb = (const float*)d_in[28];
    float* out = (float*)d_out;
    char* ws = (char*)d_ws;

    half_t* bufX = (half_t*)(ws + WS_BUFX);
    half_t* bufY = (half_t*)(ws + WS_BUFY);
    float* convf = (float*)(ws + WS_CONVF);
    half_t* wp1 = (half_t*)(ws + WS_WP1);
    half_t* wp2 = (half_t*)(ws + WS_WP2);
    float* meanb = (float*)(ws + WS_MEAN);
    float* rstdb = (float*)(ws + WS_RSTD);

    // zero mailboxes + counters + encoder ring slot 0 (per launch/replay)
    hipMemsetAsync(d_ws, 0, (size_t)WS_ZERO_BYTES, stream);

    // front-end
    k_embed<<<NROWS, 256, 0, stream>>>(x, emb, bufX);
    k_packconvw<<<(3 * EE * EE + 255) / 256, 256, 0, stream>>>(c1w, wp1);
    k_conv<<<dim3(128, 32), 256, 0, stream>>>(bufX, wp1, c1b, convf);
    k_bnstats<<<EE, 256, 0, stream>>>(convf, meanb, rstdb);
    k_bnapply<<<(NROWS * EE) / 256, 256, 0, stream>>>(convf, meanb, rstdb, bn1g, bn1b, bufY);
    k_packconvw<<<(3 * EE * EE + 255) / 256, 256, 0, stream>>>(c2w, wp2);
    k_conv<<<dim3(128, 32), 256, 0, stream>>>(bufY, wp2, c2b, convf);
    k_bnstats<<<EE, 256, 0, stream>>>(convf, meanb, rstdb);
    k_bnapply<<<(NROWS * EE) / 256, 256, 0, stream>>>(convf, meanb, rstdb, bn2g, bn2b, bufX);

    // fused: prep (hidden under enc) + encoder + decoder + mask
    k_fused<<<192, 512, 0, stream>>>(wihf, whhf, bihf, bhhf, wihb, whhb, bihb, bhhb,
                                     dwih, dwhh, dbih, dbhh, projw, projb, gatew, gateb,
                                     tlens, mlens, ws, out);

    (void)in_sizes; (void)n_in; (void)out_size; (void)ws_size;
}